// Round 1
// baseline (199.188 us; speedup 1.0000x reference)
//
#include <hip/hip_runtime.h>
#include <math.h>

// Problem constants (reference: B=2048, S=8, D=1280, K=1)
#define SV 8
#define DV 1280
#define THREADS 256
#define F4PERBATCH ((SV*DV)/4)        // 2560 float4
#define PER_T (F4PERBATCH/THREADS)    // 10 float4 per thread

__global__ __launch_bounds__(THREADS)
void cmr_kernel(const float* __restrict__ feat,
                const float* __restrict__ kp,
                const float* __restrict__ cmr_gate,
                float* __restrict__ out,
                int Bn)
{
    __shared__ __align__(16) float tile[SV * DV];   // 40 KB: the 8x1280 batch slice
    __shared__ __align__(16) float pbuf[DV];        // 5 KB : p[d] = u^T fn
    __shared__ float gsc[4][36];                    // per-wave gram partials
    __shared__ float csum[36];                      // summed raw cross-products
    __shared__ float muS[SV], sigS[SV], rsigS[SV];
    __shared__ float coefS[SV], aS[SV];
    __shared__ float bconstS;
    __shared__ float pc1S, flagS;

    const int b = blockIdx.x;
    const int tid = threadIdx.x;

    // ---- 1. stage features tile into LDS (coalesced float4) ----
    const float4* __restrict__ src4 = (const float4*)(feat + (size_t)b * SV * DV);
    float4* tile4 = (float4*)tile;
#pragma unroll
    for (int k = 0; k < PER_T; ++k)
        tile4[tid + THREADS * k] = src4[tid + THREADS * k];
    __syncthreads();

    // ---- 2. per-row mean / std (32 lanes per row; rows 2w,2w+1 per wave) ----
    {
        const int r = tid >> 5;      // 0..7
        const int l = tid & 31;
        float s = 0.f, ss = 0.f;
#pragma unroll
        for (int k = 0; k < DV / 32; ++k) {
            float v = tile[r * DV + l + 32 * k];
            s += v; ss = fmaf(v, v, ss);
        }
#pragma unroll
        for (int m = 16; m >= 1; m >>= 1) {
            s  += __shfl_xor(s,  m);
            ss += __shfl_xor(ss, m);
        }
        if (l == 0) {
            float mu  = s / (float)DV;
            float var = fmaxf(ss / (float)DV - mu * mu, 0.f);
            float sig = sqrtf(var) + 1e-8f;   // numpy std(ddof=0) + 1e-8
            muS[r] = mu; sigS[r] = sig; rsigS[r] = 1.f / sig;
        }
    }
    __syncthreads();

    // ---- 3. Gram raw cross-products C[i][j] = sum_d f_i f_j (36 upper-tri) ----
    float acc[36];
#pragma unroll
    for (int k = 0; k < 36; ++k) acc[k] = 0.f;
    for (int k = 0; k < DV / THREADS; ++k) {   // 5 chunks
        const int d = tid + THREADS * k;
        float f[8];
#pragma unroll
        for (int s = 0; s < 8; ++s) f[s] = tile[s * DV + d];
        int idx = 0;
#pragma unroll
        for (int i = 0; i < 8; ++i)
#pragma unroll
            for (int j = i; j < 8; ++j) { acc[idx] = fmaf(f[i], f[j], acc[idx]); ++idx; }
    }
#pragma unroll
    for (int m = 32; m >= 1; m >>= 1)
#pragma unroll
        for (int k = 0; k < 36; ++k) acc[k] += __shfl_xor(acc[k], m);
    {
        const int wave = tid >> 6;
        if ((tid & 63) == 0)
#pragma unroll
            for (int k = 0; k < 36; ++k) gsc[wave][k] = acc[k];
    }
    __syncthreads();
    if (tid < 36)
        csum[tid] = gsc[0][tid] + gsc[1][tid] + gsc[2][tid] + gsc[3][tid];
    __syncthreads();

    // ---- 4. top eigenpair of 8x8 G on wave 0 (lane = (i,j) entry) ----
    if (tid < 64) {
        const int i = tid >> 3, j = tid & 7;
        const int a_ = (i < j) ? i : j;
        const int b_ = (i < j) ? j : i;
        const int t_ = 8 * a_ - (a_ * (a_ - 1)) / 2 + (b_ - a_);  // upper-tri index
        const float G = (csum[t_] - (float)DV * muS[i] * muS[j]) * rsigS[i] * rsigS[j];

        // trace(G) = sum of squared singular values
        float tr = (i == j) ? G : 0.f;
#pragma unroll
        for (int m = 32; m >= 1; m >>= 1) tr += __shfl_xor(tr, m);

        // normalized matrix squaring: A <- (A/max)^2, 16 times => G^(2^16) direction
        float A = G;
        float mx = fabsf(A);
#pragma unroll
        for (int m = 32; m >= 1; m >>= 1) mx = fmaxf(mx, __shfl_xor(mx, m));
        A = A / fmaxf(mx, 1e-37f);
        for (int t = 0; t < 16; ++t) {
            float nb = 0.f;
#pragma unroll
            for (int k = 0; k < 8; ++k)
                nb = fmaf(__shfl(A, i * 8 + k), __shfl(A, k * 8 + j), nb);
            float m2 = fabsf(nb);
#pragma unroll
            for (int m = 32; m >= 1; m >>= 1) m2 = fmaxf(m2, __shfl_xor(m2, m));
            A = nb / fmaxf(m2, 1e-37f);
        }

        // pick column with largest norm -> ~u1 direction
        float cn = A * A;
#pragma unroll
        for (int m = 8; m <= 32; m <<= 1) cn += __shfl_xor(cn, m);  // sum over i
        float best = cn; int bj = j;
#pragma unroll
        for (int m = 1; m <= 4; m <<= 1) {
            float ov = __shfl_xor(best, m);
            int   oj = __shfl_xor(bj, m);
            if (ov > best || (ov == best && oj < bj)) { best = ov; bj = oj; }
        }
        float u = __shfl(A, i * 8 + bj);           // u_i (same for all j lanes)
        float nn = u * u;
#pragma unroll
        for (int m = 8; m <= 32; m <<= 1) nn += __shfl_xor(nn, m);
        u *= rsqrtf(fmaxf(nn, 1e-37f));

        // 2 power-iteration polish steps on the original G
        for (int it = 0; it < 2; ++it) {
            float yp = G * __shfl(u, j * 8);       // G[i][j] * u_j
#pragma unroll
            for (int m = 1; m <= 4; m <<= 1) yp += __shfl_xor(yp, m);  // sum over j -> y_i
            float ny = yp * yp;
#pragma unroll
            for (int m = 8; m <= 32; m <<= 1) ny += __shfl_xor(ny, m); // sum over i
            u = yp * rsqrtf(fmaxf(ny, 1e-37f));
        }

        // Rayleigh quotient lambda1 = u^T G u
        float lp = G * u * __shfl(u, j * 8);
#pragma unroll
        for (int m = 32; m >= 1; m >>= 1) lp += __shfl_xor(lp, m);
        const float lam = lp;

        // gates
        const float gate    = 1.f / (1.f + expf(-cmr_gate[0]));
        const float kp_gate = (kp[b] >= 5.0f) ? 1.5f : 1.0f;
        const float Gt      = gate * kp_gate;

        if (j == 0) {
            coefS[i] = Gt * sigS[i] * u;   // out = f - coef[s] * p[d]
            aS[i]    = u * rsigS[i];       // p[d] = sum_s aS[s]*f[s,d] - bconst
        }
        float bp = (j == 0) ? u * rsigS[i] * muS[i] : 0.f;
#pragma unroll
        for (int m = 32; m >= 1; m >>= 1) bp += __shfl_xor(bp, m);
        if (tid == 0) {
            bconstS = bp;
            const float pc1 = lam / (tr + 1e-8f);
            pc1S  = pc1;
            flagS = (pc1 >= 0.6f ? 1.f : 0.f) + (pc1 >= 0.8f ? 1.f : 0.f);
        }
    }
    __syncthreads();

    // ---- 5. p[d] = u^T fn ----
    for (int k = 0; k < DV / THREADS; ++k) {
        const int d = tid + THREADS * k;
        float p = -bconstS;
#pragma unroll
        for (int s = 0; s < 8; ++s) p = fmaf(aS[s], tile[s * DV + d], p);
        pbuf[d] = p;
    }
    __syncthreads();

    // ---- 6. epilogue: out = f - coef[s]*p[d] (coalesced float4) ----
    float4* __restrict__ dst4 = (float4*)(out + (size_t)b * SV * DV);
    const float4* pbuf4 = (const float4*)pbuf;
#pragma unroll
    for (int k = 0; k < PER_T; ++k) {
        const int e4 = tid + THREADS * k;
        const int s  = e4 / (DV / 4);       // 320 float4 per row
        const int dg = e4 % (DV / 4);
        const float c = coefS[s];
        float4 f = tile4[e4];
        float4 p = pbuf4[dg];
        float4 o;
        o.x = fmaf(-c, p.x, f.x);
        o.y = fmaf(-c, p.y, f.y);
        o.z = fmaf(-c, p.z, f.z);
        o.w = fmaf(-c, p.w, f.w);
        dst4[e4] = o;
    }

    if (tid == 0) {
        out[(size_t)Bn * SV * DV + b]      = pc1S;   // pc1_ratio
        out[(size_t)Bn * SV * DV + Bn + b] = flagS;  // solar_flag (as float)
    }
}

extern "C" void kernel_launch(void* const* d_in, const int* in_sizes, int n_in,
                              void* d_out, int out_size, void* d_ws, size_t ws_size,
                              hipStream_t stream) {
    const float* feat = (const float*)d_in[0];
    const float* kp   = (const float*)d_in[1];
    const float* gate = (const float*)d_in[2];
    const int Bn = in_sizes[0] / (SV * DV);
    cmr_kernel<<<Bn, THREADS, 0, stream>>>(feat, kp, gate, (float*)d_out, Bn);
}

// Round 2
// 179.831 us; speedup vs baseline: 1.1076x; 1.1076x over previous
//
#include <hip/hip_runtime.h>
#include <math.h>

// B=2048, S=8, D=1280, K=1 rank-1 common-mode removal.
// Split design: K1 = per-batch Gram + 8x8 top-eigenpair (1 wave/batch, no LDS,
// all cross-lane via shuffles); K2 = pure streaming apply (no LDS, no barriers).

#define SV 8
#define DV 1280
#define BSTRIDE (SV*DV)   // 10240 floats per batch
#define WSS 17            // per-batch coeffs in workspace: a[8], coef[8], bconst

__global__ __launch_bounds__(256)
void cmr_stats_kernel(const float* __restrict__ feat,
                      const float* __restrict__ kp,
                      const float* __restrict__ cmr_gate,
                      float* __restrict__ cws,
                      float* __restrict__ out,
                      int Bn)
{
    const int lane = threadIdx.x & 63;
    const int b = blockIdx.x * 4 + (threadIdx.x >> 6);   // 1 wave = 1 batch

    const float* __restrict__ fb = feat + (size_t)b * BSTRIDE;

    // ---- raw sums + upper-tri cross products, 20 columns per lane ----
    float Sr[8], C[36];
#pragma unroll
    for (int s = 0; s < 8; ++s) Sr[s] = 0.f;
#pragma unroll
    for (int t = 0; t < 36; ++t) C[t] = 0.f;

#pragma unroll
    for (int k = 0; k < DV / 64; ++k) {      // 20
        const int d = lane + 64 * k;
        float f[8];
#pragma unroll
        for (int s = 0; s < 8; ++s) f[s] = fb[s * DV + d];   // coalesced per row
#pragma unroll
        for (int s = 0; s < 8; ++s) Sr[s] += f[s];
        int idx = 0;
#pragma unroll
        for (int i = 0; i < 8; ++i)
#pragma unroll
            for (int j = i; j < 8; ++j) { C[idx] = fmaf(f[i], f[j], C[idx]); ++idx; }
    }
    // butterfly-reduce all 44 partials across the wave (all lanes get totals)
#pragma unroll
    for (int m = 32; m >= 1; m >>= 1) {
#pragma unroll
        for (int s = 0; s < 8; ++s) Sr[s] += __shfl_xor(Sr[s], m);
#pragma unroll
        for (int t = 0; t < 36; ++t) C[t] += __shfl_xor(C[t], m);
    }

    // ---- lane (i,j) builds its Gram entry G[i][j] of normalized rows ----
    const int i = lane >> 3, j = lane & 7;
    const int a_ = (i < j) ? i : j;
    const int b_ = (i < j) ? j : i;
    const int tii = 8 * i - (i * (i - 1)) / 2;
    const int tjj = 8 * j - (j * (j - 1)) / 2;
    const int tij = 8 * a_ - (a_ * (a_ - 1)) / 2 + (b_ - a_);

    float Ci = 0.f, Cj = 0.f, Cij = 0.f, Si = 0.f, Sj = 0.f;
#pragma unroll
    for (int t = 0; t < 36; ++t) {
        Ci  = (t == tii) ? C[t] : Ci;
        Cj  = (t == tjj) ? C[t] : Cj;
        Cij = (t == tij) ? C[t] : Cij;
    }
#pragma unroll
    for (int s = 0; s < 8; ++s) {
        Si = (s == i) ? Sr[s] : Si;
        Sj = (s == j) ? Sr[s] : Sj;
    }
    const float invD = 1.f / (float)DV;
    const float mui = Si * invD, muj = Sj * invD;
    const float vari = fmaxf(Ci * invD - mui * mui, 0.f);
    const float varj = fmaxf(Cj * invD - muj * muj, 0.f);
    const float sigi = sqrtf(vari) + 1e-8f;          // numpy std(ddof=0)+1e-8
    const float sigj = sqrtf(varj) + 1e-8f;
    const float rsigi = 1.f / sigi, rsigj = 1.f / sigj;
    const float G = ((Cij - (float)DV * mui * muj) * rsigi) * rsigj;

    // trace (= sum of squared singular values)
    float tr = (i == j) ? G : 0.f;
#pragma unroll
    for (int m = 32; m >= 1; m >>= 1) tr += __shfl_xor(tr, m);
    const float trs = fmaxf(tr, 1e-30f);

    // ---- top eigenpair: 14x normalized squaring (trace renorm: overflow-proof,
    //      |A_ij| <= sqrt(Aii*Ajj) <= trace) + diag-argmax column pick + 2 polish
    float A = G / trs;
#pragma unroll
    for (int t = 0; t < 14; ++t) {
        float nb = 0.f;
#pragma unroll
        for (int k = 0; k < 8; ++k)
            nb = fmaf(__shfl(A, i * 8 + k), __shfl(A, k * 8 + j), nb);
        float dg = (i == j) ? nb : 0.f;
#pragma unroll
        for (int m = 32; m >= 1; m >>= 1) dg += __shfl_xor(dg, m);
        A = nb / fmaxf(dg, 1e-30f);
    }

    // argmax over diagonal (diag of PSD power ~ c*u_i^2; max >= 1/8 after renorm)
    float dv = (i == j) ? A : -1.f;
    int bj = j;
#pragma unroll
    for (int m = 32; m >= 1; m >>= 1) {
        float ov = __shfl_xor(dv, m);
        int   oj = __shfl_xor(bj, m);
        if (ov > dv) { dv = ov; bj = oj; }
    }
    float u = __shfl(A, i * 8 + bj);                 // ~u_i (all lanes of row i)
    {
        float nn = (j == 0) ? u * u : 0.f;
#pragma unroll
        for (int m = 32; m >= 1; m >>= 1) nn += __shfl_xor(nn, m);
        u *= rsqrtf(fmaxf(nn, 1e-30f));
    }
    // 2 power-iteration polish steps on G
#pragma unroll
    for (int it = 0; it < 2; ++it) {
        float y = G * __shfl(u, j * 8);              // G[i][j]*u_j
#pragma unroll
        for (int m = 1; m <= 4; m <<= 1) y += __shfl_xor(y, m);   // row-sum -> y_i
        float ny = (j == 0) ? y * y : 0.f;
#pragma unroll
        for (int m = 32; m >= 1; m >>= 1) ny += __shfl_xor(ny, m);
        u = y * rsqrtf(fmaxf(ny, 1e-30f));
    }
    // Rayleigh quotient
    float lp = G * u * __shfl(u, j * 8);
#pragma unroll
    for (int m = 32; m >= 1; m >>= 1) lp += __shfl_xor(lp, m);
    const float pc1 = lp / (tr + 1e-8f);

    // gates
    const float gate = 1.f / (1.f + expf(-cmr_gate[0]));
    const float kpg  = (kp[b] >= 5.0f) ? 1.5f : 1.0f;
    const float Gt   = gate * kpg;

    // bconst = sum_s u_s * rsig_s * mu_s
    float bcp = (j == 0) ? u * rsigi * mui : 0.f;
#pragma unroll
    for (int m = 32; m >= 1; m >>= 1) bcp += __shfl_xor(bcp, m);

    float* wsb = cws + (size_t)b * WSS;
    if (j == 0) {
        wsb[i]     = u * rsigi;        // a_i   : p[d] = sum a_s f[s,d] - bconst
        wsb[8 + i] = Gt * sigi * u;    // coef_i: out = f - coef_s * p[d]
    }
    if (lane == 0) {
        wsb[16] = bcp;
        out[(size_t)Bn * BSTRIDE + b] = pc1;
        const float flag = (pc1 >= 0.6f ? 1.f : 0.f) + (pc1 >= 0.8f ? 1.f : 0.f);
        out[(size_t)Bn * BSTRIDE + Bn + b] = flag;
    }
}

__global__ __launch_bounds__(256)
void cmr_apply_kernel(const float* __restrict__ feat,
                      const float* __restrict__ cws,
                      float* __restrict__ out)
{
    const int lane = threadIdx.x & 63;
    const int b = blockIdx.x * 4 + (threadIdx.x >> 6);   // 1 wave = 1 batch

    const float* __restrict__ wsb = cws + (size_t)b * WSS;
    float a[8], c[8];
#pragma unroll
    for (int s = 0; s < 8; ++s) { a[s] = wsb[s]; c[s] = wsb[8 + s]; }
    const float bc = wsb[16];

    const float4* __restrict__ f4 = (const float4*)(feat + (size_t)b * BSTRIDE);
    float4* __restrict__ o4 = (float4*)(out + (size_t)b * BSTRIDE);

#pragma unroll
    for (int k = 0; k < 5; ++k) {                 // 320 float4 per row / 64 lanes
        const int d4 = lane + 64 * k;
        float4 f[8];
#pragma unroll
        for (int s = 0; s < 8; ++s) f[s] = f4[s * (DV / 4) + d4];
        float4 p = make_float4(-bc, -bc, -bc, -bc);
#pragma unroll
        for (int s = 0; s < 8; ++s) {
            p.x = fmaf(a[s], f[s].x, p.x);
            p.y = fmaf(a[s], f[s].y, p.y);
            p.z = fmaf(a[s], f[s].z, p.z);
            p.w = fmaf(a[s], f[s].w, p.w);
        }
#pragma unroll
        for (int s = 0; s < 8; ++s) {
            float4 o;
            o.x = fmaf(-c[s], p.x, f[s].x);
            o.y = fmaf(-c[s], p.y, f[s].y);
            o.z = fmaf(-c[s], p.z, f[s].z);
            o.w = fmaf(-c[s], p.w, f[s].w);
            o4[s * (DV / 4) + d4] = o;
        }
    }
}

extern "C" void kernel_launch(void* const* d_in, const int* in_sizes, int n_in,
                              void* d_out, int out_size, void* d_ws, size_t ws_size,
                              hipStream_t stream) {
    const float* feat = (const float*)d_in[0];
    const float* kp   = (const float*)d_in[1];
    const float* gate = (const float*)d_in[2];
    float* out = (float*)d_out;
    float* cws = (float*)d_ws;
    const int Bn = in_sizes[0] / BSTRIDE;       // 2048

    cmr_stats_kernel<<<Bn / 4, 256, 0, stream>>>(feat, kp, gate, cws, out, Bn);
    cmr_apply_kernel<<<Bn / 4, 256, 0, stream>>>(feat, cws, out);
}